// Round 3
// baseline (96.880 us; speedup 1.0000x reference)
//
#include <hip/hip_runtime.h>

// PartChamferLoss: src/dst [B=16, K=8, 3, 1024] f32 -> scalar f32.
// Pass 1: partial d2-mins, 8 queries/thread, 4-way target split, plain stores to ws.
// Pass 2: min across splits, clamp, sqrt, global sum.
// Inner-loop trick: min_n(s + sq_n - 2 dot) = s + min_n(sq_n - 2 dot) -> 4 ops/pair.

#define NPTS 1024
#define NSPLIT 4
#define TPB1 128
#define TGT_PER_SPLIT (NPTS / NSPLIT)  // 256
#define QPT 8                           // 1024 queries / 128 threads

__global__ __launch_bounds__(TPB1) void chamfer_partial_kernel(
    const float* __restrict__ src,  // [BK, 3, NPTS]
    const float* __restrict__ dst,  // [BK, 3, NPTS]
    float* __restrict__ ws,         // [NSPLIT, 2*BK, NPTS] partial d2 mins
    int BK) {
  __shared__ float4 tgt[TGT_PER_SPLIT];  // x, y, z, x^2+y^2+z^2  (4 KB)

  const int task = blockIdx.x;
  const int split = task & (NSPLIT - 1);
  const int pair = task >> 2;          // dir*BK + bk, flat in [0, 2*BK)
  const int dir = pair >= BK;
  const int bk = dir ? (pair - BK) : pair;

  const float* A = (dir ? dst : src) + (size_t)bk * 3 * NPTS;   // queries
  const float* Bb = (dir ? src : dst) + (size_t)bk * 3 * NPTS;  // targets
  const int tid = threadIdx.x;

  // Stage this block's 256-target quarter into LDS (coalesced).
  const int n0 = split * TGT_PER_SPLIT;
  for (int i = tid; i < TGT_PER_SPLIT; i += TPB1) {
    float x = Bb[n0 + i];
    float y = Bb[NPTS + n0 + i];
    float z = Bb[2 * NPTS + n0 + i];
    tgt[i] = make_float4(x, y, z, fmaf(x, x, fmaf(y, y, z * z)));
  }
  __syncthreads();

  // 8 query points per thread: m_j = j*128 + tid.
  float ax[QPT], ay[QPT], az[QPT], sq[QPT], mn[QPT];
#pragma unroll
  for (int j = 0; j < QPT; ++j) {
    const int m = j * TPB1 + tid;
    float x = A[m], y = A[NPTS + m], z = A[2 * NPTS + m];
    ax[j] = -2.0f * x;
    ay[j] = -2.0f * y;
    az[j] = -2.0f * z;
    sq[j] = fmaf(x, x, fmaf(y, y, z * z));
    mn[j] = 3.4e38f;
  }

#pragma unroll 4
  for (int n = 0; n < TGT_PER_SPLIT; ++n) {
    float4 d = tgt[n];  // wave-uniform address -> broadcast, conflict-free
#pragma unroll
    for (int j = 0; j < QPT; ++j) {
      // sq_n - 2*dot : query-constant sq[j] hoisted out of the loop
      float t = fmaf(ax[j], d.x, fmaf(ay[j], d.y, fmaf(az[j], d.z, d.w)));
      mn[j] = fminf(mn[j], t);
    }
  }

  // Plain coalesced stores of partial d2 mins: ws[split][pair][q]
  float* wrow = ws + ((size_t)split * (2 * BK) + pair) * NPTS;
#pragma unroll
  for (int j = 0; j < QPT; ++j) {
    wrow[j * TPB1 + tid] = sq[j] + mn[j];
  }
}

__global__ __launch_bounds__(256) void chamfer_finish_kernel(
    const float* __restrict__ ws, float* __restrict__ out,
    int QT,  // total queries = 2*BK*NPTS
    float scale) {
  const int g = blockIdx.x * 256 + threadIdx.x;
  float v = ws[g];
#pragma unroll
  for (int s = 1; s < NSPLIT; ++s) v = fminf(v, ws[(size_t)s * QT + g]);
  v = sqrtf(fmaxf(v, 0.0f));

  // Wave64 reduce, then cross-wave via LDS, one atomic per block.
  for (int off = 32; off > 0; off >>= 1) v += __shfl_down(v, off);
  __shared__ float wsum[4];
  const int tid = threadIdx.x;
  if ((tid & 63) == 0) wsum[tid >> 6] = v;
  __syncthreads();
  if (tid == 0) {
    float s = 0.0f;
#pragma unroll
    for (int w = 0; w < 4; ++w) s += wsum[w];
    atomicAdd(out, s * scale);
  }
}

extern "C" void kernel_launch(void* const* d_in, const int* in_sizes, int n_in,
                              void* d_out, int out_size, void* d_ws, size_t ws_size,
                              hipStream_t stream) {
  const float* src = (const float*)d_in[0];  // [B,K,3,M]
  const float* dst = (const float*)d_in[1];  // [B,K,3,N]
  float* out = (float*)d_out;                // scalar f32
  float* ws = (float*)d_ws;                  // >= 4 MB scratch

  const int BK = in_sizes[0] / (3 * NPTS);        // 16*8 = 128
  const int QT = 2 * BK * NPTS;                   // 262144
  const float scale = 1.0f / (float)(BK * NPTS);  // 1/(B*K*M), M==N

  // d_out is re-poisoned to 0xAA before every timed launch — zero it.
  hipMemsetAsync(out, 0, sizeof(float), stream);

  dim3 grid1(2 * BK * NSPLIT);  // 1024 blocks of 128 threads
  chamfer_partial_kernel<<<grid1, TPB1, 0, stream>>>(src, dst, ws, BK);

  dim3 grid2(QT / 256);  // 1024 blocks of 256 threads
  chamfer_finish_kernel<<<grid2, 256, 0, stream>>>(ws, out, QT, scale);
}

// Round 4
// 85.533 us; speedup vs baseline: 1.1327x; 1.1327x over previous
//
#include <hip/hip_runtime.h>

// PartChamferLoss: src/dst [B=16, K=8, 3, 1024] f32 -> scalar f32.
// Pass 1: partial d2-mins. NSPLIT=8 target splits -> 2048 blocks of 128
//         (8 blocks/CU = 4 waves/SIMD for latency hiding). 8 queries/thread.
// Pass 2: vectorized min across splits + sqrt + sum; 128 blocks, 128 atomics.
// Inner trick: min_n(sq_q + sq_n - 2 dot) = sq_q + min_n(sq_n - 2 dot) -> 4 ops/pair.

#define NPTS 1024
#define NSPLIT 8
#define TPB1 128
#define TGT_PER_SPLIT (NPTS / NSPLIT)  // 128
#define QPT 8                          // 1024 queries / 128 threads

__global__ __launch_bounds__(TPB1) void chamfer_partial_kernel(
    const float* __restrict__ src,  // [BK, 3, NPTS]
    const float* __restrict__ dst,  // [BK, 3, NPTS]
    float* __restrict__ ws,         // [NSPLIT, 2*BK, NPTS] partial d2 mins
    int BK) {
  __shared__ float4 tgt[TGT_PER_SPLIT];  // x, y, z, x^2+y^2+z^2  (2 KB)

  const int task = blockIdx.x;
  const int split = task & (NSPLIT - 1);
  const int pair = task >> 3;          // dir*BK + bk, flat in [0, 2*BK)
  const int dir = pair >= BK;
  const int bk = dir ? (pair - BK) : pair;

  const float* A = (dir ? dst : src) + (size_t)bk * 3 * NPTS;   // queries
  const float* Bb = (dir ? src : dst) + (size_t)bk * 3 * NPTS;  // targets
  const int tid = threadIdx.x;

  // Stage this block's 128-target slice into LDS (one coalesced round).
  {
    const int i = tid;  // TPB1 == TGT_PER_SPLIT
    const int n = split * TGT_PER_SPLIT + i;
    float x = Bb[n];
    float y = Bb[NPTS + n];
    float z = Bb[2 * NPTS + n];
    tgt[i] = make_float4(x, y, z, fmaf(x, x, fmaf(y, y, z * z)));
  }
  __syncthreads();

  // 8 query points per thread: m_j = j*128 + tid.  Arrays are fully
  // unrolled -> compile-time indices -> registers (never scratch).
  float ax[QPT], ay[QPT], az[QPT], sq[QPT], mn[QPT];
#pragma unroll
  for (int j = 0; j < QPT; ++j) {
    const int m = j * TPB1 + tid;
    float x = A[m], y = A[NPTS + m], z = A[2 * NPTS + m];
    ax[j] = -2.0f * x;
    ay[j] = -2.0f * y;
    az[j] = -2.0f * z;
    sq[j] = fmaf(x, x, fmaf(y, y, z * z));
    mn[j] = 3.4e38f;
  }

#pragma unroll 8
  for (int n = 0; n < TGT_PER_SPLIT; ++n) {
    float4 d = tgt[n];  // wave-uniform address -> broadcast, conflict-free
#pragma unroll
    for (int j = 0; j < QPT; ++j) {
      float t = fmaf(ax[j], d.x, fmaf(ay[j], d.y, fmaf(az[j], d.z, d.w)));
      mn[j] = fminf(mn[j], t);
    }
  }

  // Plain coalesced stores of partial d2 mins: ws[split][pair][q]
  float* wrow = ws + ((size_t)split * (2 * BK) + pair) * NPTS;
#pragma unroll
  for (int j = 0; j < QPT; ++j) {
    wrow[j * TPB1 + tid] = sq[j] + mn[j];
  }
}

// Pass 2: each thread owns 8 CONSECUTIVE queries (2x float4 per split),
// mins across the 8 splits, sqrt, sums. 128 blocks -> 128 atomics.
#define TPB2 256
#define QPT2 8

__global__ __launch_bounds__(TPB2) void chamfer_finish_kernel(
    const float* __restrict__ ws, float* __restrict__ out,
    int QT,  // total queries = 2*BK*NPTS
    float scale) {
  const int g4 = (blockIdx.x * TPB2 + threadIdx.x) * (QPT2 / 4);  // float4 idx
  const float4* ws4 = (const float4*)ws;
  const int QT4 = QT >> 2;

  float4 a = ws4[g4];
  float4 b = ws4[g4 + 1];
#pragma unroll
  for (int s = 1; s < NSPLIT; ++s) {
    float4 ua = ws4[(size_t)s * QT4 + g4];
    float4 ub = ws4[(size_t)s * QT4 + g4 + 1];
    a.x = fminf(a.x, ua.x); a.y = fminf(a.y, ua.y);
    a.z = fminf(a.z, ua.z); a.w = fminf(a.w, ua.w);
    b.x = fminf(b.x, ub.x); b.y = fminf(b.y, ub.y);
    b.z = fminf(b.z, ub.z); b.w = fminf(b.w, ub.w);
  }
  float v = sqrtf(fmaxf(a.x, 0.0f)) + sqrtf(fmaxf(a.y, 0.0f)) +
            sqrtf(fmaxf(a.z, 0.0f)) + sqrtf(fmaxf(a.w, 0.0f)) +
            sqrtf(fmaxf(b.x, 0.0f)) + sqrtf(fmaxf(b.y, 0.0f)) +
            sqrtf(fmaxf(b.z, 0.0f)) + sqrtf(fmaxf(b.w, 0.0f));

  // Wave64 reduce, then cross-wave via LDS, one atomic per block.
  for (int off = 32; off > 0; off >>= 1) v += __shfl_down(v, off);
  __shared__ float wsum[TPB2 / 64];
  const int tid = threadIdx.x;
  if ((tid & 63) == 0) wsum[tid >> 6] = v;
  __syncthreads();
  if (tid == 0) {
    float s = 0.0f;
#pragma unroll
    for (int w = 0; w < TPB2 / 64; ++w) s += wsum[w];
    atomicAdd(out, s * scale);
  }
}

extern "C" void kernel_launch(void* const* d_in, const int* in_sizes, int n_in,
                              void* d_out, int out_size, void* d_ws, size_t ws_size,
                              hipStream_t stream) {
  const float* src = (const float*)d_in[0];  // [B,K,3,M]
  const float* dst = (const float*)d_in[1];  // [B,K,3,N]
  float* out = (float*)d_out;                // scalar f32
  float* ws = (float*)d_ws;                  // >= 8 MB scratch

  const int BK = in_sizes[0] / (3 * NPTS);        // 16*8 = 128
  const int QT = 2 * BK * NPTS;                   // 262144
  const float scale = 1.0f / (float)(BK * NPTS);  // 1/(B*K*M), M==N

  // d_out is re-poisoned to 0xAA before every timed launch — zero it.
  hipMemsetAsync(out, 0, sizeof(float), stream);

  dim3 grid1(2 * BK * NSPLIT);  // 2048 blocks of 128 threads
  chamfer_partial_kernel<<<grid1, TPB1, 0, stream>>>(src, dst, ws, BK);

  dim3 grid2(QT / (TPB2 * QPT2));  // 128 blocks of 256 threads
  chamfer_finish_kernel<<<grid2, TPB2, 0, stream>>>(ws, out, QT, scale);
}

// Round 5
// 78.860 us; speedup vs baseline: 1.2285x; 1.0846x over previous
//
#include <hip/hip_runtime.h>

// PartChamferLoss: src/dst [B=16, K=8, 3, 1024] f32 -> scalar f32.
// SINGLE kernel. One block = one (bk, dir) pair. 1024 threads =
// 8 target-splits x 128 query-groups. Each thread: 8 queries x 128 targets
// from its split's LDS slice (wave-uniform broadcast reads).
// Cross-split min combined in LDS via atomicMin on uint-ordered nonneg floats.
// Inner trick: min_n(sq_q + sq_n - 2 dot) = sq_q + min_n(sq_n - 2 dot).

#define NPTS 1024
#define TPB 1024
#define NSPLIT 8
#define QPT 8
#define TGT (NPTS / NSPLIT)  // 128 targets per split

__global__ __launch_bounds__(TPB) void chamfer_onepass_kernel(
    const float* __restrict__ src,  // [BK, 3, NPTS]
    const float* __restrict__ dst,  // [BK, 3, NPTS]
    float* __restrict__ out, int BK, float scale) {
  __shared__ float4 tgt[NPTS];     // 16 KB: x, y, z, x^2+y^2+z^2
  __shared__ unsigned cmb[NPTS];   // 4 KB: [j][qg] = j*128 + qg (conflict-free)
  __shared__ float wsum[2];

  const int t = threadIdx.x;
  const int pair = blockIdx.x;          // dir*BK + bk
  const int dir = pair >= BK;
  const int bk = dir ? (pair - BK) : pair;
  const float* A = (dir ? dst : src) + (size_t)bk * 3 * NPTS;   // queries
  const float* Bb = (dir ? src : dst) + (size_t)bk * 3 * NPTS;  // targets

  // Stage all 1024 targets (1 per thread, coalesced); init combine buf to +inf.
  {
    float x = Bb[t], y = Bb[NPTS + t], z = Bb[2 * NPTS + t];
    tgt[t] = make_float4(x, y, z, fmaf(x, x, fmaf(y, y, z * z)));
    cmb[t] = 0x7F800000u;  // +inf (all finite nonneg d2 compare below this)
  }
  __syncthreads();

  const int qg = t & 127;      // query group: queries qg + j*128
  const int split = t >> 7;    // wave-uniform (64 | 128)

  // 8 query points per thread (fully unrolled -> registers).
  float ax[QPT], ay[QPT], az[QPT], sq[QPT], mn[QPT];
#pragma unroll
  for (int j = 0; j < QPT; ++j) {
    const int m = qg + j * 128;
    float x = A[m], y = A[NPTS + m], z = A[2 * NPTS + m];
    ax[j] = -2.0f * x;
    ay[j] = -2.0f * y;
    az[j] = -2.0f * z;
    sq[j] = fmaf(x, x, fmaf(y, y, z * z));
    mn[j] = 3.4e38f;
  }

  const float4* ts = &tgt[split * TGT];
#pragma unroll 8
  for (int n = 0; n < TGT; ++n) {
    float4 d = ts[n];  // wave-uniform address -> LDS broadcast, no conflict
#pragma unroll
    for (int j = 0; j < QPT; ++j) {
      float v = fmaf(ax[j], d.x, fmaf(ay[j], d.y, fmaf(az[j], d.z, d.w)));
      mn[j] = fminf(mn[j], v);
    }
  }

  // Clamp to >=0 then uint-ordered LDS atomic-min across the 8 splits.
#pragma unroll
  for (int j = 0; j < QPT; ++j) {
    float m = fmaxf(sq[j] + mn[j], 0.0f);
    atomicMin(&cmb[j * 128 + qg], __float_as_uint(m));
  }
  __syncthreads();

  // Waves 0-1: sqrt + sum the 1024 final mins; one atomic per block.
  if (t < 128) {
    float v = 0.0f;
#pragma unroll
    for (int j = 0; j < QPT; ++j)
      v += sqrtf(__uint_as_float(cmb[j * 128 + t]));
    for (int off = 32; off > 0; off >>= 1) v += __shfl_down(v, off);
    if ((t & 63) == 0) wsum[t >> 6] = v;
  }
  __syncthreads();
  if (t == 0) atomicAdd(out, (wsum[0] + wsum[1]) * scale);
}

extern "C" void kernel_launch(void* const* d_in, const int* in_sizes, int n_in,
                              void* d_out, int out_size, void* d_ws, size_t ws_size,
                              hipStream_t stream) {
  const float* src = (const float*)d_in[0];  // [B,K,3,M]
  const float* dst = (const float*)d_in[1];  // [B,K,3,N]
  float* out = (float*)d_out;                // scalar f32

  const int BK = in_sizes[0] / (3 * NPTS);        // 16*8 = 128
  const float scale = 1.0f / (float)(BK * NPTS);  // 1/(B*K*M), M==N

  // d_out is re-poisoned to 0xAA before every timed launch — zero it.
  hipMemsetAsync(out, 0, sizeof(float), stream);

  dim3 grid(2 * BK);  // 256 blocks of 1024 threads: 1 block/CU, 4 waves/SIMD
  chamfer_onepass_kernel<<<grid, TPB, 0, stream>>>(src, dst, out, BK, scale);
}

// Round 6
// 76.970 us; speedup vs baseline: 1.2587x; 1.0246x over previous
//
#include <hip/hip_runtime.h>

// PartChamferLoss: src/dst [B=16, K=8, 3, 1024] f32 -> scalar f32.
// Main kernel: one block = one (bk,dir) pair; 1024 thr = 8 splits x 128 qgroups;
//   8 queries/thread (as 4x v2f for v_pk_fma_f32) x 128-target LDS slice.
//   Cross-split min via LDS atomicMin (uint-ordered nonneg floats).
//   Block partial -> PLAIN store to ws[block] (no same-address global atomics).
// Finisher: 1 block reduces 256 partials, stores out[0] (no memset needed).

typedef float v2f __attribute__((ext_vector_type(2)));

#define NPTS 1024
#define TPB 1024
#define NSPLIT 8
#define QPT 8
#define QP2 (QPT / 2)
#define TGT (NPTS / NSPLIT)  // 128 targets per split

__global__ __launch_bounds__(TPB) void chamfer_main_kernel(
    const float* __restrict__ src,  // [BK, 3, NPTS]
    const float* __restrict__ dst,  // [BK, 3, NPTS]
    float* __restrict__ part,       // [2*BK] block partials
    int BK) {
  __shared__ float4 tgt[NPTS];     // 16 KB: x, y, z, x^2+y^2+z^2
  __shared__ unsigned cmb[NPTS];   // 4 KB: [j][qg], conflict-free
  __shared__ float wsum[2];

  const int t = threadIdx.x;
  const int pair = blockIdx.x;          // dir*BK + bk
  const int dir = pair >= BK;
  const int bk = dir ? (pair - BK) : pair;
  const float* A = (dir ? dst : src) + (size_t)bk * 3 * NPTS;   // queries
  const float* Bb = (dir ? src : dst) + (size_t)bk * 3 * NPTS;  // targets

  // Stage all 1024 targets (coalesced); init combine buf to +inf.
  {
    float x = Bb[t], y = Bb[NPTS + t], z = Bb[2 * NPTS + t];
    tgt[t] = make_float4(x, y, z, fmaf(x, x, fmaf(y, y, z * z)));
    cmb[t] = 0x7F800000u;  // +inf
  }
  __syncthreads();

  const int qg = t & 127;    // query group: queries qg + j*128
  const int split = t >> 7;  // wave-uniform

  // 8 queries/thread packed as 4x v2f (targets v_pk_fma_f32 on the chains).
  v2f ax[QP2], ay[QP2], az[QP2], sq[QP2], mn[QP2];
#pragma unroll
  for (int p = 0; p < QP2; ++p) {
    const int m0 = qg + (2 * p) * 128, m1 = qg + (2 * p + 1) * 128;
    float x0 = A[m0], y0 = A[NPTS + m0], z0 = A[2 * NPTS + m0];
    float x1 = A[m1], y1 = A[NPTS + m1], z1 = A[2 * NPTS + m1];
    ax[p] = (v2f){-2.0f * x0, -2.0f * x1};
    ay[p] = (v2f){-2.0f * y0, -2.0f * y1};
    az[p] = (v2f){-2.0f * z0, -2.0f * z1};
    sq[p] = (v2f){fmaf(x0, x0, fmaf(y0, y0, z0 * z0)),
                  fmaf(x1, x1, fmaf(y1, y1, z1 * z1))};
    mn[p] = (v2f){3.4e38f, 3.4e38f};
  }

  const float4* ts = &tgt[split * TGT];
#pragma unroll 8
  for (int n = 0; n < TGT; ++n) {
    float4 d = ts[n];  // wave-uniform address -> LDS broadcast, no conflict
    v2f dx = {d.x, d.x}, dy = {d.y, d.y}, dz = {d.z, d.z}, dw = {d.w, d.w};
#pragma unroll
    for (int p = 0; p < QP2; ++p) {
      v2f v = __builtin_elementwise_fma(az[p], dz, dw);
      v = __builtin_elementwise_fma(ay[p], dy, v);
      v = __builtin_elementwise_fma(ax[p], dx, v);
      mn[p].x = fminf(mn[p].x, v.x);  // no pk_min on CDNA -> scalar mins
      mn[p].y = fminf(mn[p].y, v.y);
    }
  }

  // Clamp >=0, then uint-ordered LDS atomicMin across the 8 splits.
  // Lane addresses are consecutive (qg) -> bank-conflict-free.
#pragma unroll
  for (int p = 0; p < QP2; ++p) {
    v2f m2 = sq[p] + mn[p];
    float a = fmaxf(m2.x, 0.0f), b = fmaxf(m2.y, 0.0f);
    atomicMin(&cmb[(2 * p) * 128 + qg], __float_as_uint(a));
    atomicMin(&cmb[(2 * p + 1) * 128 + qg], __float_as_uint(b));
  }
  __syncthreads();

  // Waves 0-1: sqrt + sum the 1024 final mins; one plain store per block.
  if (t < 128) {
    float v = 0.0f;
#pragma unroll
    for (int j = 0; j < QPT; ++j)
      v += sqrtf(__uint_as_float(cmb[j * 128 + t]));
    for (int off = 32; off > 0; off >>= 1) v += __shfl_down(v, off);
    if ((t & 63) == 0) wsum[t >> 6] = v;
  }
  __syncthreads();
  if (t == 0) part[pair] = wsum[0] + wsum[1];
}

__global__ __launch_bounds__(256) void chamfer_final_kernel(
    const float* __restrict__ part, float* __restrict__ out, int n,
    float scale) {
  const int t = threadIdx.x;
  float v = (t < n) ? part[t] : 0.0f;
  for (int off = 32; off > 0; off >>= 1) v += __shfl_down(v, off);
  __shared__ float wsum[4];
  if ((t & 63) == 0) wsum[t >> 6] = v;
  __syncthreads();
  if (t == 0) out[0] = (wsum[0] + wsum[1] + wsum[2] + wsum[3]) * scale;
}

extern "C" void kernel_launch(void* const* d_in, const int* in_sizes, int n_in,
                              void* d_out, int out_size, void* d_ws, size_t ws_size,
                              hipStream_t stream) {
  const float* src = (const float*)d_in[0];  // [B,K,3,M]
  const float* dst = (const float*)d_in[1];  // [B,K,3,N]
  float* out = (float*)d_out;                // scalar f32
  float* part = (float*)d_ws;                // 256 floats of scratch

  const int BK = in_sizes[0] / (3 * NPTS);        // 16*8 = 128
  const float scale = 1.0f / (float)(BK * NPTS);  // 1/(B*K*M), M==N

  dim3 grid(2 * BK);  // 256 blocks of 1024 threads
  chamfer_main_kernel<<<grid, TPB, 0, stream>>>(src, dst, part, BK);
  chamfer_final_kernel<<<1, 256, 0, stream>>>(part, out, 2 * BK, scale);
}